// Round 4
// baseline (433.026 us; speedup 1.0000x reference)
//
#include <hip/hip_runtime.h>
#include <hip/hip_bf16.h>

// transformAttention fused MFMA kernel (round 4)
// Block = (b, 8-n tile), 512 thr = 8 waves, LDS 36.9 KB -> 4 blocks/CU.
//   phase 1: q/k/v projections via mfma_f32_16x16x32_bf16; M-tile = 2s x 8n rows;
//            C -> LDS bf16 slabs [t][s][n][d], XOR swizzle ((n&4)<<3)^((s&1)<<6).
//   phase 2: attention, 1 n per wave, lane = d, 8-lane butterfly; no max-sub
//            (scores tiny by construction), v_rcp instead of div.
//   phase 3: FFN, 6 M-tiles of 16 rows (= 2s x 8n) on waves 0..5, through an
//            XOR-swizzled f32 [96][64] overlay on the dead q/k slabs.
//   phase 4: coalesced 256B/row output stores (fixes round-3's 1.9x write amp).

typedef __attribute__((ext_vector_type(8))) short bf16x8;
typedef __attribute__((ext_vector_type(4))) float f32x4;

constexpr int Bb = 16, Ss = 12, Nn = 2048, Dd = 64;
constexpr float SCALE = 0.35355339059327373f; // 1/sqrt(8)

#define MFMA16(A, B, C) __builtin_amdgcn_mfma_f32_16x16x32_bf16((A), (B), (C), 0, 0, 0)

__device__ __forceinline__ short f2bf(float f) {
    __hip_bfloat16 h = __float2bfloat16(f);
    short s;
    __builtin_memcpy(&s, &h, 2);
    return s;
}
__device__ __forceinline__ float bf2f(short v) {
    unsigned u = ((unsigned)(unsigned short)v) << 16;
    float f;
    __builtin_memcpy(&f, &u, 4);
    return f;
}
__device__ __forceinline__ void lds_fence() {
    asm volatile("s_waitcnt lgkmcnt(0)" ::: "memory");
    __builtin_amdgcn_sched_barrier(0);
}
// qkv slab byte offset (bf16): t*12288 + s*1024 + n*128 + ((2d)^((n&4)<<3)^((s&1)<<6))
__device__ __forceinline__ int qkvOfs(int t, int s, int n, int d) {
    return t * 12288 + s * 1024 + n * 128 + ((2 * d) ^ ((n & 4) << 3) ^ ((s & 1) << 6));
}
// FFN overlay byte offset (f32, 96 rows x 64 cols over bytes [0, 24576))
__device__ __forceinline__ int bofs(int row, int col) {
    return row * 256 + ((col * 4) ^ ((row & 7) << 4));
}

__global__ __launch_bounds__(512, 8)
void ta_mfma2(const float* __restrict__ x,
              const float* __restrict__ steP,
              const float* __restrict__ steQ,
              const float* __restrict__ Wff, const float* __restrict__ bff,
              const float* __restrict__ W1,  const float* __restrict__ b1,
              const float* __restrict__ W2,  const float* __restrict__ b2,
              float* __restrict__ out)
{
    alignas(16) __shared__ char smem[36864];

    const int tid = threadIdx.x;
    const int w   = tid >> 6;
    const int l   = tid & 63;
    const int l15 = l & 15;
    const int l4  = l >> 4;
    const int b   = blockIdx.y;
    const int n0  = blockIdx.x * 8;

    // ---- W_ff B-frags: lane holds W[kc*32 + l4*8 + j][nt*16 + l15] ----
    bf16x8 wf[4][2];
    float bfv[4];
    #pragma unroll
    for (int nt = 0; nt < 4; ++nt) {
        bfv[nt] = bff[nt * 16 + l15];
        #pragma unroll
        for (int kc = 0; kc < 2; ++kc)
            #pragma unroll
            for (int j = 0; j < 8; ++j)
                wf[nt][kc][j] = f2bf(Wff[(kc * 32 + l4 * 8 + j) * 64 + nt * 16 + l15]);
    }

    // ---- phase 1: projections, 18 jobs = 3 tensors x 6 s-pairs ----
    const int sA = l15 >> 3, nA = l15 & 7;   // A-frag row -> (sLocal, n)
    for (int job = w; job < 18; job += 8) {
        const int t = job / 6, s0 = (job % 6) * 2;
        const float* base = (t == 0) ? steQ : (t == 1) ? steP : x;
        const float* rp = base + ((size_t)(b * Ss + s0 + sA) * Nn + n0 + nA) * Dd + l4 * 8;

        bf16x8 a[2];
        #pragma unroll
        for (int kc = 0; kc < 2; ++kc) {
            float4 p0 = *(const float4*)(rp + kc * 32);
            float4 p1 = *(const float4*)(rp + kc * 32 + 4);
            a[kc][0] = f2bf(p0.x); a[kc][1] = f2bf(p0.y);
            a[kc][2] = f2bf(p0.z); a[kc][3] = f2bf(p0.w);
            a[kc][4] = f2bf(p1.x); a[kc][5] = f2bf(p1.y);
            a[kc][6] = f2bf(p1.z); a[kc][7] = f2bf(p1.w);
        }
        #pragma unroll
        for (int nt = 0; nt < 4; ++nt) {
            f32x4 acc = { bfv[nt], bfv[nt], bfv[nt], bfv[nt] };
            acc = MFMA16(a[0], wf[nt][0], acc);
            acc = MFMA16(a[1], wf[nt][1], acc);
            const int d = nt * 16 + l15;
            #pragma unroll
            for (int q = 0; q < 4; ++q) {
                const int r = l4 * 4 + q;
                *(short*)(smem + qkvOfs(t, s0 + (r >> 3), r & 7, d)) = f2bf(acc[q]);
            }
        }
    }
    __syncthreads();

    // ---- phase 2: attention, n = w, lane = d ----
    const int n = w;
    float qv[12], kv[12];
    #pragma unroll
    for (int s = 0; s < 12; ++s) {
        const int off = qkvOfs(0, s, n, 0) + ((2 * l) ^ ((n & 4) << 3));
        // note: qkvOfs(t,s,n,0) already applies the s/n XORs; add lane d-term:
        qv[s] = bf2f(*(const short*)(smem + qkvOfs(0, s, n, l)));
        kv[s] = bf2f(*(const short*)(smem + qkvOfs(1, s, n, l)));
        (void)off;
    }
    __syncthreads();   // barrier1: q,k slabs dead -> overlay writable

    float vv[12];
    #pragma unroll
    for (int s = 0; s < 12; ++s)
        vv[s] = bf2f(*(const short*)(smem + qkvOfs(2, s, n, l)));

    #pragma unroll
    for (int r = 0; r < 12; ++r) {
        float tt[12];
        #pragma unroll
        for (int p = 0; p < 12; ++p) tt[p] = qv[r] * kv[p];
        #pragma unroll
        for (int p = 0; p < 12; ++p) {
            tt[p] += __shfl_xor(tt[p], 1);
            tt[p] += __shfl_xor(tt[p], 2);
            tt[p] += __shfl_xor(tt[p], 4);
        }
        float sum = 0.f, o = 0.f;
        #pragma unroll
        for (int p = 0; p < 12; ++p) { tt[p] = __expf(tt[p] * SCALE); sum += tt[p]; }
        #pragma unroll
        for (int p = 0; p < 12; ++p) o = fmaf(tt[p], vv[p], o);
        float inv;
        asm("v_rcp_f32 %0, %1" : "=v"(inv) : "v"(sum));
        const int row = r * 8 + w;                 // buf row = qIdx*8 + n
        *(float*)(smem + bofs(row, l)) = o * inv;
    }
    __syncthreads();   // barrier2: overlay (attn) complete

    // ---- phase 3: FFN, waves 0..5 own 16-row tiles ----
    if (w < 6) {
        const int tb = w * 16;

        bf16x8 w1f[4][2];
        float b1v[4];
        #pragma unroll
        for (int nt = 0; nt < 4; ++nt) {
            b1v[nt] = b1[nt * 16 + l15];
            #pragma unroll
            for (int kc = 0; kc < 2; ++kc)
                #pragma unroll
                for (int j = 0; j < 8; ++j)
                    w1f[nt][kc][j] = f2bf(W1[(kc * 32 + l4 * 8 + j) * 64 + nt * 16 + l15]);
        }

        bf16x8 a[2];
        #pragma unroll
        for (int kc = 0; kc < 2; ++kc) {
            const int row = tb + l15, c0 = kc * 32 + l4 * 8;
            float4 p0 = *(const float4*)(smem + bofs(row, c0));
            float4 p1 = *(const float4*)(smem + bofs(row, c0 + 4));
            a[kc][0] = f2bf(p0.x); a[kc][1] = f2bf(p0.y);
            a[kc][2] = f2bf(p0.z); a[kc][3] = f2bf(p0.w);
            a[kc][4] = f2bf(p1.x); a[kc][5] = f2bf(p1.y);
            a[kc][6] = f2bf(p1.z); a[kc][7] = f2bf(p1.w);
        }
        f32x4 hh[4];
        #pragma unroll
        for (int nt = 0; nt < 4; ++nt) {
            f32x4 acc = { b1v[nt], b1v[nt], b1v[nt], b1v[nt] };
            acc = MFMA16(a[0], w1f[nt][0], acc);
            acc = MFMA16(a[1], w1f[nt][1], acc);
            #pragma unroll
            for (int q = 0; q < 4; ++q) hh[nt][q] = fmaxf(acc[q], 0.f);
        }
        #pragma unroll
        for (int nt = 0; nt < 4; ++nt)
            #pragma unroll
            for (int q = 0; q < 4; ++q)
                *(float*)(smem + bofs(tb + l4 * 4 + q, nt * 16 + l15)) = hh[nt][q];
        lds_fence();   // hid writes before re-reads (compiler ordering)

        bf16x8 w2f[4][2];
        float b2v[4];
        #pragma unroll
        for (int nt = 0; nt < 4; ++nt) {
            b2v[nt] = b2[nt * 16 + l15];
            #pragma unroll
            for (int kc = 0; kc < 2; ++kc)
                #pragma unroll
                for (int j = 0; j < 8; ++j)
                    w2f[nt][kc][j] = f2bf(W2[(kc * 32 + l4 * 8 + j) * 64 + nt * 16 + l15]);
        }
        #pragma unroll
        for (int kc = 0; kc < 2; ++kc) {
            const int row = tb + l15, c0 = kc * 32 + l4 * 8;
            float4 p0 = *(const float4*)(smem + bofs(row, c0));
            float4 p1 = *(const float4*)(smem + bofs(row, c0 + 4));
            a[kc][0] = f2bf(p0.x); a[kc][1] = f2bf(p0.y);
            a[kc][2] = f2bf(p0.z); a[kc][3] = f2bf(p0.w);
            a[kc][4] = f2bf(p1.x); a[kc][5] = f2bf(p1.y);
            a[kc][6] = f2bf(p1.z); a[kc][7] = f2bf(p1.w);
        }
        #pragma unroll
        for (int nt = 0; nt < 4; ++nt) {
            f32x4 acc = { b2v[nt], b2v[nt], b2v[nt], b2v[nt] };
            acc = MFMA16(a[0], w2f[nt][0], acc);
            acc = MFMA16(a[1], w2f[nt][1], acc);
            #pragma unroll
            for (int q = 0; q < 4; ++q)
                *(float*)(smem + bofs(tb + l4 * 4 + q, nt * 16 + l15)) = acc[q];
        }
    }
    __syncthreads();   // barrier3: FFN output in overlay

    // ---- phase 4: coalesced stores, 12 rows per wave, 256B contiguous ----
    #pragma unroll
    for (int i = 0; i < 12; ++i) {
        const int row = w * 12 + i;
        const int s = row >> 3, nl = row & 7;
        const float v = *(const float*)(smem + bofs(row, l));
        out[((size_t)(b * Ss + s) * Nn + n0 + nl) * Dd + l] = v;
    }
}

extern "C" void kernel_launch(void* const* d_in, const int* in_sizes, int n_in,
                              void* d_out, int out_size, void* d_ws, size_t ws_size,
                              hipStream_t stream) {
    const float* x    = (const float*)d_in[0];
    const float* steP = (const float*)d_in[1];
    const float* steQ = (const float*)d_in[2];
    const float* Wff  = (const float*)d_in[3];
    const float* bff  = (const float*)d_in[4];
    const float* W1   = (const float*)d_in[5];
    const float* b1   = (const float*)d_in[6];
    const float* W2   = (const float*)d_in[7];
    const float* b2   = (const float*)d_in[8];
    float* out = (float*)d_out;

    dim3 grid(Nn / 8, Bb);
    ta_mfma2<<<grid, 512, 0, stream>>>(x, steP, steQ, Wff, bff, W1, b1, W2, b2, out);
}

// Round 5
// 203.388 us; speedup vs baseline: 2.1291x; 2.1291x over previous
//
#include <hip/hip_runtime.h>
#include <hip/hip_bf16.h>

// transformAttention fused MFMA kernel (round 5)
// Round 4 post-mortem: __launch_bounds__(512,8) forced a 64-VGPR cap -> allocator
// spilled to scratch (FETCH 516MB / WRITE 944MB vs 302/96 ideal) -> 433us.
// Round 5 = round-4 structure with (512,4): no spills; occupancy self-selects
// (4 blocks/CU if allocator lands <=64 VGPR, else 2 = round-3 parity + write fix).
// Block = (b, 8-n tile), 512 thr = 8 waves, LDS 36.9 KB.
//   phase 1: q/k/v projections via mfma_f32_16x16x32_bf16, M-tile = 2s x 8n;
//   phase 2: attention, 1 n per wave, lane = d, 8-lane butterfly, no max-sub,
//            v_rcp for 1/sum;
//   phase 3: FFN on 6 waves, 16-row M-tiles through XOR-swizzled f32 overlay;
//   phase 4: coalesced 256B/row stores.

typedef __attribute__((ext_vector_type(8))) short bf16x8;
typedef __attribute__((ext_vector_type(4))) float f32x4;

constexpr int Bb = 16, Ss = 12, Nn = 2048, Dd = 64;
constexpr float SCALE = 0.35355339059327373f; // 1/sqrt(8)

#define MFMA16(A, B, C) __builtin_amdgcn_mfma_f32_16x16x32_bf16((A), (B), (C), 0, 0, 0)

__device__ __forceinline__ short f2bf(float f) {
    __hip_bfloat16 h = __float2bfloat16(f);
    short s;
    __builtin_memcpy(&s, &h, 2);
    return s;
}
__device__ __forceinline__ float bf2f(short v) {
    unsigned u = ((unsigned)(unsigned short)v) << 16;
    float f;
    __builtin_memcpy(&f, &u, 4);
    return f;
}
__device__ __forceinline__ void lds_fence() {
    asm volatile("s_waitcnt lgkmcnt(0)" ::: "memory");
    __builtin_amdgcn_sched_barrier(0);
}
// qkv slab byte offset (bf16): t*12288 + s*1024 + n*128 + ((2d)^((n&4)<<3)^((s&1)<<6))
__device__ __forceinline__ int qkvOfs(int t, int s, int n, int d) {
    return t * 12288 + s * 1024 + n * 128 + ((2 * d) ^ ((n & 4) << 3) ^ ((s & 1) << 6));
}
// FFN overlay byte offset (f32, 96 rows x 64 cols over bytes [0, 24576))
__device__ __forceinline__ int bofs(int row, int col) {
    return row * 256 + ((col * 4) ^ ((row & 7) << 4));
}

__global__ __launch_bounds__(512, 4)
void ta_mfma3(const float* __restrict__ x,
              const float* __restrict__ steP,
              const float* __restrict__ steQ,
              const float* __restrict__ Wff, const float* __restrict__ bff,
              const float* __restrict__ W1,  const float* __restrict__ b1,
              const float* __restrict__ W2,  const float* __restrict__ b2,
              float* __restrict__ out)
{
    alignas(16) __shared__ char smem[36864];

    const int tid = threadIdx.x;
    const int w   = tid >> 6;
    const int l   = tid & 63;
    const int l15 = l & 15;
    const int l4  = l >> 4;
    const int b   = blockIdx.y;
    const int n0  = blockIdx.x * 8;

    // ---- W_ff B-frags: lane holds W[kc*32 + l4*8 + j][nt*16 + l15] ----
    bf16x8 wf[4][2];
    float bfv[4];
    #pragma unroll
    for (int nt = 0; nt < 4; ++nt) {
        bfv[nt] = bff[nt * 16 + l15];
        #pragma unroll
        for (int kc = 0; kc < 2; ++kc)
            #pragma unroll
            for (int j = 0; j < 8; ++j)
                wf[nt][kc][j] = f2bf(Wff[(kc * 32 + l4 * 8 + j) * 64 + nt * 16 + l15]);
    }

    // ---- phase 1: projections, 18 jobs = 3 tensors x 6 s-pairs ----
    const int sA = l15 >> 3, nA = l15 & 7;   // A-frag row -> (sLocal, n)
    for (int job = w; job < 18; job += 8) {
        const int t = job / 6, s0 = (job % 6) * 2;
        const float* base = (t == 0) ? steQ : (t == 1) ? steP : x;
        const float* rp = base + ((size_t)(b * Ss + s0 + sA) * Nn + n0 + nA) * Dd + l4 * 8;

        bf16x8 a[2];
        #pragma unroll
        for (int kc = 0; kc < 2; ++kc) {
            float4 p0 = *(const float4*)(rp + kc * 32);
            float4 p1 = *(const float4*)(rp + kc * 32 + 4);
            a[kc][0] = f2bf(p0.x); a[kc][1] = f2bf(p0.y);
            a[kc][2] = f2bf(p0.z); a[kc][3] = f2bf(p0.w);
            a[kc][4] = f2bf(p1.x); a[kc][5] = f2bf(p1.y);
            a[kc][6] = f2bf(p1.z); a[kc][7] = f2bf(p1.w);
        }
        #pragma unroll
        for (int nt = 0; nt < 4; ++nt) {
            f32x4 acc = { bfv[nt], bfv[nt], bfv[nt], bfv[nt] };
            acc = MFMA16(a[0], wf[nt][0], acc);
            acc = MFMA16(a[1], wf[nt][1], acc);
            const int d = nt * 16 + l15;
            #pragma unroll
            for (int q = 0; q < 4; ++q) {
                const int r = l4 * 4 + q;
                *(short*)(smem + qkvOfs(t, s0 + (r >> 3), r & 7, d)) = f2bf(acc[q]);
            }
        }
    }
    __syncthreads();

    // ---- phase 2: attention, n = w, lane = d ----
    const int n = w;
    float qv[12], kv[12];
    #pragma unroll
    for (int s = 0; s < 12; ++s) {
        qv[s] = bf2f(*(const short*)(smem + qkvOfs(0, s, n, l)));
        kv[s] = bf2f(*(const short*)(smem + qkvOfs(1, s, n, l)));
    }
    __syncthreads();   // barrier1: q,k slabs dead -> overlay writable

    float vv[12];
    #pragma unroll
    for (int s = 0; s < 12; ++s)
        vv[s] = bf2f(*(const short*)(smem + qkvOfs(2, s, n, l)));

    #pragma unroll
    for (int r = 0; r < 12; ++r) {
        float tt[12];
        #pragma unroll
        for (int p = 0; p < 12; ++p) tt[p] = qv[r] * kv[p];
        #pragma unroll
        for (int p = 0; p < 12; ++p) {
            tt[p] += __shfl_xor(tt[p], 1);
            tt[p] += __shfl_xor(tt[p], 2);
            tt[p] += __shfl_xor(tt[p], 4);
        }
        float sum = 0.f, o = 0.f;
        #pragma unroll
        for (int p = 0; p < 12; ++p) { tt[p] = __expf(tt[p] * SCALE); sum += tt[p]; }
        #pragma unroll
        for (int p = 0; p < 12; ++p) o = fmaf(tt[p], vv[p], o);
        float inv;
        asm("v_rcp_f32 %0, %1" : "=v"(inv) : "v"(sum));
        const int row = r * 8 + w;                 // buf row = qIdx*8 + n
        *(float*)(smem + bofs(row, l)) = o * inv;
    }
    __syncthreads();   // barrier2: overlay (attn) complete

    // ---- phase 3: FFN, waves 0..5 own 16-row tiles ----
    if (w < 6) {
        const int tb = w * 16;

        bf16x8 w1f[4][2];
        float b1v[4];
        #pragma unroll
        for (int nt = 0; nt < 4; ++nt) {
            b1v[nt] = b1[nt * 16 + l15];
            #pragma unroll
            for (int kc = 0; kc < 2; ++kc)
                #pragma unroll
                for (int j = 0; j < 8; ++j)
                    w1f[nt][kc][j] = f2bf(W1[(kc * 32 + l4 * 8 + j) * 64 + nt * 16 + l15]);
        }

        bf16x8 a[2];
        #pragma unroll
        for (int kc = 0; kc < 2; ++kc) {
            const int row = tb + l15, c0 = kc * 32 + l4 * 8;
            float4 p0 = *(const float4*)(smem + bofs(row, c0));
            float4 p1 = *(const float4*)(smem + bofs(row, c0 + 4));
            a[kc][0] = f2bf(p0.x); a[kc][1] = f2bf(p0.y);
            a[kc][2] = f2bf(p0.z); a[kc][3] = f2bf(p0.w);
            a[kc][4] = f2bf(p1.x); a[kc][5] = f2bf(p1.y);
            a[kc][6] = f2bf(p1.z); a[kc][7] = f2bf(p1.w);
        }
        f32x4 hh[4];
        #pragma unroll
        for (int nt = 0; nt < 4; ++nt) {
            f32x4 acc = { b1v[nt], b1v[nt], b1v[nt], b1v[nt] };
            acc = MFMA16(a[0], w1f[nt][0], acc);
            acc = MFMA16(a[1], w1f[nt][1], acc);
            #pragma unroll
            for (int q = 0; q < 4; ++q) hh[nt][q] = fmaxf(acc[q], 0.f);
        }
        #pragma unroll
        for (int nt = 0; nt < 4; ++nt)
            #pragma unroll
            for (int q = 0; q < 4; ++q)
                *(float*)(smem + bofs(tb + l4 * 4 + q, nt * 16 + l15)) = hh[nt][q];
        lds_fence();   // hid writes before re-reads (compiler ordering)

        bf16x8 w2f[4][2];
        float b2v[4];
        #pragma unroll
        for (int nt = 0; nt < 4; ++nt) {
            b2v[nt] = b2[nt * 16 + l15];
            #pragma unroll
            for (int kc = 0; kc < 2; ++kc)
                #pragma unroll
                for (int j = 0; j < 8; ++j)
                    w2f[nt][kc][j] = f2bf(W2[(kc * 32 + l4 * 8 + j) * 64 + nt * 16 + l15]);
        }
        #pragma unroll
        for (int kc = 0; kc < 2; ++kc) {
            const int row = tb + l15, c0 = kc * 32 + l4 * 8;
            float4 p0 = *(const float4*)(smem + bofs(row, c0));
            float4 p1 = *(const float4*)(smem + bofs(row, c0 + 4));
            a[kc][0] = f2bf(p0.x); a[kc][1] = f2bf(p0.y);
            a[kc][2] = f2bf(p0.z); a[kc][3] = f2bf(p0.w);
            a[kc][4] = f2bf(p1.x); a[kc][5] = f2bf(p1.y);
            a[kc][6] = f2bf(p1.z); a[kc][7] = f2bf(p1.w);
        }
        #pragma unroll
        for (int nt = 0; nt < 4; ++nt) {
            f32x4 acc = { b2v[nt], b2v[nt], b2v[nt], b2v[nt] };
            acc = MFMA16(a[0], w2f[nt][0], acc);
            acc = MFMA16(a[1], w2f[nt][1], acc);
            #pragma unroll
            for (int q = 0; q < 4; ++q)
                *(float*)(smem + bofs(tb + l4 * 4 + q, nt * 16 + l15)) = acc[q];
        }
    }
    __syncthreads();   // barrier3: FFN output in overlay

    // ---- phase 4: coalesced stores, 12 rows per wave, 256B contiguous ----
    for (int i = 0; i < 12; ++i) {
        const int row = w * 12 + i;
        const int s = row >> 3, nl = row & 7;
        const float v = *(const float*)(smem + bofs(row, l));
        out[((size_t)(b * Ss + s) * Nn + n0 + nl) * Dd + l] = v;
    }
}

extern "C" void kernel_launch(void* const* d_in, const int* in_sizes, int n_in,
                              void* d_out, int out_size, void* d_ws, size_t ws_size,
                              hipStream_t stream) {
    const float* x    = (const float*)d_in[0];
    const float* steP = (const float*)d_in[1];
    const float* steQ = (const float*)d_in[2];
    const float* Wff  = (const float*)d_in[3];
    const float* bff  = (const float*)d_in[4];
    const float* W1   = (const float*)d_in[5];
    const float* b1   = (const float*)d_in[6];
    const float* W2   = (const float*)d_in[7];
    const float* b2   = (const float*)d_in[8];
    float* out = (float*)d_out;

    dim3 grid(Nn / 8, Bb);
    ta_mfma3<<<grid, 512, 0, stream>>>(x, steP, steQ, Wff, bff, W1, b1, W2, b2, out);
}

// Round 6
// 161.603 us; speedup vs baseline: 2.6796x; 1.2586x over previous
//
#include <hip/hip_runtime.h>
#include <hip/hip_bf16.h>

// transformAttention fused MFMA kernel (round 6)
// Round-5 post-mortem: VALU-issue-bound (~4K cyc/wave), dominated by butterfly
// attention (144 exps + 432 shfls/wave) and scalar W-frag loads (+cvts).
// Round 6: per-head MFMA attention (zero-padded k-slots via LDS zero block),
// swapped QK^T (S^T: softmax over p = 3 adds + 2 shfls, 32 exps/wave),
// P in regs -> ds_bpermute to PV A-frag, V stored transposed (p-padded 16),
// weights pre-transposed to bf16 in d_ws by a tiny prep kernel.
// LDS (49168 B, 3 blocks/CU):
//   [0,12288)      q slab [12s][8n][64d] bf16 swz   -> attn-out bf16 [96][64] swz
//   [12288,24576)  k slab                            -> hid bf16 [96][64] swz
//   [24576,40960)  vT [8n][64d][16p] bf16 (p>=12 =0) -> outbuf f32 [96][64] swz (to 49152)
//   [49152,49168)  zero block (MFMA k-slot padding)

typedef __attribute__((ext_vector_type(8))) short bf16x8;
typedef __attribute__((ext_vector_type(4))) float f32x4;

constexpr int Bb = 16, Ss = 12, Nn = 2048, Dd = 64;
constexpr float EXPK = 0.51011687f;   // (1/sqrt(8)) * log2(e)
constexpr int KOFS = 12288, VTOFS = 24576, OBOFS = 24576, ZOFS = 49152, LDSZ = 49168;

#define MFMA16(A, B, C) __builtin_amdgcn_mfma_f32_16x16x32_bf16((A), (B), (C), 0, 0, 0)

__device__ __forceinline__ short f2bf(float f) {
    __hip_bfloat16 h = __float2bfloat16(f);
    short s; __builtin_memcpy(&s, &h, 2); return s;
}
__device__ __forceinline__ unsigned cvtpk(float lo, float hi) {
    unsigned r;
    asm("v_cvt_pk_bf16_f32 %0, %1, %2" : "=v"(r) : "v"(lo), "v"(hi));
    return r;
}
// q/k slab byte offset
__device__ __forceinline__ int qkOfs(int t, int s, int n, int d) {
    return t * 12288 + s * 1024 + n * 128 +
           ((2 * d) ^ ((n & 4) << 3) ^ ((s & 1) << 6) ^ ((s & 2) << 4));
}
// attn-out / hid bf16 [96 rows][64 d]
__device__ __forceinline__ int aOfs(int row, int d) {
    return row * 128 + ((2 * d) ^ (((row >> 3) & 7) << 4));
}
// outbuf f32 [96 rows][64 col]
__device__ __forceinline__ int oOfs(int row, int col) {
    return OBOFS + row * 256 + ((4 * col) ^ (((row >> 3) & 7) << 5));
}
// vT bf16 [8 n][64 d][16 p]
__device__ __forceinline__ int vtOfs(int n, int d, int p) {
    return VTOFS + ((n * 64 + d) * 16 + p) * 2;
}

// prep: d_ws <- bf16 W^T for Wff, W1, W2 (each 64x64): Wt[m][colOut*64 + kIn]
__global__ void prep_w(const float* __restrict__ Wff, const float* __restrict__ W1,
                       const float* __restrict__ W2, unsigned short* __restrict__ wt) {
    int idx = blockIdx.x * 256 + threadIdx.x;      // 48 blocks x 256
    if (idx >= 3 * 4096) return;
    int m = idx >> 12, rc = idx & 4095, r = rc >> 6, c = rc & 63;
    const float* W = (m == 0) ? Wff : (m == 1) ? W1 : W2;
    unsigned short u; short s = f2bf(W[c * 64 + r]);
    __builtin_memcpy(&u, &s, 2);
    wt[idx] = u;                                    // wt[m][r*64 + c] = W[c][r]
}

__global__ __launch_bounds__(512, 4)
void ta_mfma4(const float* __restrict__ x,
              const float* __restrict__ steP,
              const float* __restrict__ steQ,
              const float* __restrict__ bff, const float* __restrict__ b1,
              const float* __restrict__ b2,
              const unsigned short* __restrict__ wt,
              float* __restrict__ out)
{
    alignas(16) __shared__ char smem[LDSZ];

    const int tid = threadIdx.x;
    const int w   = tid >> 6;
    const int l   = tid & 63;
    const int l15 = l & 15;
    const int l4  = l >> 4;
    const int b   = blockIdx.y;
    const int n0  = blockIdx.x * 8;

    // zero block + vT p-pad zeros ((n*64+d) == tid covers all 512)
    if (tid < 4) *(float*)(smem + ZOFS + tid * 4) = 0.f;
    *(long long*)(smem + VTOFS + tid * 32 + 24) = 0LL;

    // ---- W_ff B-frags (bf16, pre-transposed in d_ws) ----
    bf16x8 wf[4][2];
    float bfv[4];
    #pragma unroll
    for (int nt = 0; nt < 4; ++nt) {
        bfv[nt] = bff[nt * 16 + l15];
        #pragma unroll
        for (int kc = 0; kc < 2; ++kc)
            wf[nt][kc] = *(const bf16x8*)(wt + (nt * 16 + l15) * 64 + kc * 32 + l4 * 8);
    }

    // ---- phase 1: projections, 18 jobs = 3 tensors x 6 s-pairs ----
    const int sA = l15 >> 3, nA = l15 & 7;
    for (int job = w; job < 18; job += 8) {
        const int t = job / 6, s0 = (job % 6) * 2;
        const float* base = (t == 0) ? steQ : (t == 1) ? steP : x;
        const float* rp = base + ((size_t)(b * Ss + s0 + sA) * Nn + n0 + nA) * Dd + l4 * 8;

        bf16x8 a[2];
        #pragma unroll
        for (int kc = 0; kc < 2; ++kc) {
            float4 p0 = *(const float4*)(rp + kc * 32);
            float4 p1 = *(const float4*)(rp + kc * 32 + 4);
            union { unsigned u[4]; bf16x8 v; } cv;
            cv.u[0] = cvtpk(p0.x, p0.y); cv.u[1] = cvtpk(p0.z, p0.w);
            cv.u[2] = cvtpk(p1.x, p1.y); cv.u[3] = cvtpk(p1.z, p1.w);
            a[kc] = cv.v;
        }
        #pragma unroll
        for (int nt = 0; nt < 4; ++nt) {
            f32x4 acc = { bfv[nt], bfv[nt], bfv[nt], bfv[nt] };
            acc = MFMA16(a[0], wf[nt][0], acc);
            acc = MFMA16(a[1], wf[nt][1], acc);
            const int d = nt * 16 + l15;
            #pragma unroll
            for (int q = 0; q < 4; ++q) {
                const int r = l4 * 4 + q, s = s0 + (r >> 3), nn = r & 7;
                if (t < 2) *(short*)(smem + qkOfs(t, s, nn, d)) = f2bf(acc[q]);
                else       *(short*)(smem + vtOfs(nn, d, s))   = f2bf(acc[q]);
            }
        }
    }
    __syncthreads();   // B1: q,k,vT ready

    // ---- phase 2a: per-head QK^T (swapped) + softmax; P packed in regs ----
    const int n = w;
    unsigned pw[8][2];
    #pragma unroll
    for (int h = 0; h < 8; ++h) {
        const int ka = (l4 == 0) ? qkOfs(1, l15, n, h * 8) : ZOFS;
        const int qa = (l4 == 0) ? qkOfs(0, l15, n, h * 8) : ZOFS;
        bf16x8 ak = *(const bf16x8*)(smem + ka);
        bf16x8 aq = *(const bf16x8*)(smem + qa);
        f32x4 c = { 0.f, 0.f, 0.f, 0.f };
        c = MFMA16(ak, aq, c);     // S^T: row p = l4*4+reg, col q = l15
        float e[4];
        #pragma unroll
        for (int i = 0; i < 4; ++i) {
            float v = exp2f(c[i] * EXPK);
            e[i] = (l4 == 3) ? 0.f : v;     // zero p >= 12
        }
        float ssum = (e[0] + e[1]) + (e[2] + e[3]);
        ssum += __shfl_xor(ssum, 16);
        ssum += __shfl_xor(ssum, 32);
        float inv;
        asm("v_rcp_f32 %0, %1" : "=v"(inv) : "v"(ssum));
        pw[h][0] = cvtpk(e[0] * inv, e[1] * inv);
        pw[h][1] = cvtpk(e[2] * inv, e[3] * inv);
    }
    __syncthreads();   // B2: q,k slabs dead -> attn-out overlay writable

    // ---- phase 2b: PV per head; A-frag via ds_bpermute; out -> attn-out bf16 ----
    const int i0 = (32 * l4 + l15) * 4;
    #pragma unroll
    for (int h = 0; h < 8; ++h) {
        union { unsigned u[4]; bf16x8 v; } ap;
        ap.u[0] = (unsigned)__builtin_amdgcn_ds_bpermute(i0,      (int)pw[h][0]);
        ap.u[1] = (unsigned)__builtin_amdgcn_ds_bpermute(i0,      (int)pw[h][1]);
        ap.u[2] = (unsigned)__builtin_amdgcn_ds_bpermute(i0 + 64, (int)pw[h][0]);
        ap.u[3] = (unsigned)__builtin_amdgcn_ds_bpermute(i0 + 64, (int)pw[h][1]);
        if (l4 >= 2) { ap.u[0] = 0; ap.u[1] = 0; ap.u[2] = 0; ap.u[3] = 0; }
        const int va = (l15 < 8 && l4 < 2) ? vtOfs(n, h * 8 + l15, l4 * 8) : ZOFS;
        bf16x8 bv = *(const bf16x8*)(smem + va);
        f32x4 o = { 0.f, 0.f, 0.f, 0.f };
        o = MFMA16(ap.v, bv, o);   // rows q = l4*4+reg, cols d' = l15 (<8 valid)
        if (l15 < 8) {
            #pragma unroll
            for (int reg = 0; reg < 4; ++reg) {
                const int q = l4 * 4 + reg;
                if (q < 12)
                    *(short*)(smem + aOfs(q * 8 + n, h * 8 + l15)) = f2bf(o[reg]);
            }
        }
    }
    __syncthreads();   // B3: attn-out complete

    // ---- phase 3: FFN, 12-row tiles x 8 waves ----
    const int tb = w * 12;
    {
        bf16x8 w1f[4][2];
        float b1v[4];
        #pragma unroll
        for (int nt = 0; nt < 4; ++nt) {
            b1v[nt] = b1[nt * 16 + l15];
            #pragma unroll
            for (int kc = 0; kc < 2; ++kc)
                w1f[nt][kc] = *(const bf16x8*)(wt + 4096 + (nt * 16 + l15) * 64 + kc * 32 + l4 * 8);
        }
        bf16x8 a[2];
        #pragma unroll
        for (int kc = 0; kc < 2; ++kc)
            a[kc] = *(const bf16x8*)(smem + aOfs(tb + l15, kc * 32 + l4 * 8));
        #pragma unroll
        for (int nt = 0; nt < 4; ++nt) {
            f32x4 acc = { b1v[nt], b1v[nt], b1v[nt], b1v[nt] };
            acc = MFMA16(a[0], w1f[nt][0], acc);
            acc = MFMA16(a[1], w1f[nt][1], acc);
            #pragma unroll
            for (int reg = 0; reg < 4; ++reg) {
                const int rt = l4 * 4 + reg;
                if (rt < 12)
                    *(short*)(smem + KOFS + aOfs(tb + rt, nt * 16 + l15)) =
                        f2bf(fmaxf(acc[reg], 0.f));
            }
        }
    }
    __syncthreads();   // B4: hid complete (cross-wave A-frag reads below)
    {
        bf16x8 w2f[4][2];
        float b2v[4];
        #pragma unroll
        for (int nt = 0; nt < 4; ++nt) {
            b2v[nt] = b2[nt * 16 + l15];
            #pragma unroll
            for (int kc = 0; kc < 2; ++kc)
                w2f[nt][kc] = *(const bf16x8*)(wt + 8192 + (nt * 16 + l15) * 64 + kc * 32 + l4 * 8);
        }
        bf16x8 a[2];
        #pragma unroll
        for (int kc = 0; kc < 2; ++kc)
            a[kc] = *(const bf16x8*)(smem + KOFS + aOfs(tb + l15, kc * 32 + l4 * 8));
        #pragma unroll
        for (int nt = 0; nt < 4; ++nt) {
            f32x4 acc = { b2v[nt], b2v[nt], b2v[nt], b2v[nt] };
            acc = MFMA16(a[0], w2f[nt][0], acc);
            acc = MFMA16(a[1], w2f[nt][1], acc);
            #pragma unroll
            for (int reg = 0; reg < 4; ++reg) {
                const int rt = l4 * 4 + reg;
                if (rt < 12)
                    *(float*)(smem + oOfs(tb + rt, nt * 16 + l15)) = acc[reg];
            }
        }
    }
    __syncthreads();   // B5: outbuf complete

    // ---- phase 4: coalesced float4 stores (4 rows x 256B per instr) ----
    #pragma unroll
    for (int i = 0; i < 3; ++i) {
        const int row = w * 12 + i * 4 + l4;
        const int s = row >> 3, nl = row & 7;
        f32x4 v = *(const f32x4*)(smem + oOfs(row, l15 * 4));
        *(f32x4*)(out + ((size_t)(b * Ss + s) * Nn + n0 + nl) * Dd + l15 * 4) = v;
    }
}

extern "C" void kernel_launch(void* const* d_in, const int* in_sizes, int n_in,
                              void* d_out, int out_size, void* d_ws, size_t ws_size,
                              hipStream_t stream) {
    const float* x    = (const float*)d_in[0];
    const float* steP = (const float*)d_in[1];
    const float* steQ = (const float*)d_in[2];
    const float* Wff  = (const float*)d_in[3];
    const float* bff  = (const float*)d_in[4];
    const float* W1   = (const float*)d_in[5];
    const float* b1   = (const float*)d_in[6];
    const float* W2   = (const float*)d_in[7];
    const float* b2   = (const float*)d_in[8];
    float* out = (float*)d_out;
    unsigned short* wt = (unsigned short*)d_ws;

    prep_w<<<48, 256, 0, stream>>>(Wff, W1, W2, wt);
    dim3 grid(Nn / 8, Bb);
    ta_mfma4<<<grid, 512, 0, stream>>>(x, steP, steQ, bff, b1, b2, wt, out);
}

// Round 7
// 157.037 us; speedup vs baseline: 2.7575x; 1.0291x over previous
//
#include <hip/hip_runtime.h>
#include <hip/hip_bf16.h>

// transformAttention fused MFMA kernel (round 7)
// Round-6 post-mortem: 12.2M LDS bank-conflict cycles (phase-2a stride-1024
// reads, 4-way), 3 blocks/CU, 5-barrier lockstep.
// Round 7: (s&7)<<4 q/k swizzle (2a reads conflict-free, broadcast across l4),
// zero-block removed (A-frag zeroing via cndmask) -> LDS 40960 B = 4 blocks/CU,
// FFN made wave-private (per-wave transpose buffer in dead q/k slab, no
// barriers after B2; direct global stores). Math identical to round 6.
// LDS map:
//   [0,12288)      q slab [12s][8n][64d] bf16, swz (2d)^((s&7)<<4)
//   [12288,24576)  k slab (same layout)          | after B2: per-wave tbuf
//   [24576,40960)  vT [8n][64d][16p] bf16 (p 12..15 zero-padded)
//   tbuf(w) = [w*3072, w*3072+2048): [16 rows][64 d] bf16, swz (2d)^((r&7)<<4)

typedef __attribute__((ext_vector_type(8))) short bf16x8;
typedef __attribute__((ext_vector_type(4))) float f32x4;

constexpr int Bb = 16, Ss = 12, Nn = 2048, Dd = 64;
constexpr float EXPK = 0.51011687f;   // (1/sqrt(8)) * log2(e)
constexpr int KOFS = 12288, VTOFS = 24576, LDSZ = 40960;

#define MFMA16(A, B, C) __builtin_amdgcn_mfma_f32_16x16x32_bf16((A), (B), (C), 0, 0, 0)

__device__ __forceinline__ short f2bf(float f) {
    __hip_bfloat16 h = __float2bfloat16(f);
    short s; __builtin_memcpy(&s, &h, 2); return s;
}
__device__ __forceinline__ unsigned cvtpk(float lo, float hi) {
    unsigned r;
    asm("v_cvt_pk_bf16_f32 %0, %1, %2" : "=v"(r) : "v"(lo), "v"(hi));
    return r;
}
__device__ __forceinline__ void lds_fence() {
    asm volatile("s_waitcnt lgkmcnt(0)" ::: "memory");
    __builtin_amdgcn_sched_barrier(0);
}
// q/k slab byte offset
__device__ __forceinline__ int qkOfs(int t, int s, int n, int d) {
    return t * KOFS + s * 1024 + n * 128 + ((2 * d) ^ ((s & 7) << 4));
}
// vT bf16 [8 n][64 d][16 p]
__device__ __forceinline__ int vtOfs(int n, int d, int p) {
    return VTOFS + ((n * 64 + d) * 16 + p) * 2;
}
// per-wave transpose buffer [16 rows][64 d] bf16
__device__ __forceinline__ int tOfs(int w, int row, int d) {
    return w * 3072 + row * 128 + ((2 * d) ^ ((row & 7) << 4));
}

// prep: d_ws <- bf16 W^T for Wff, W1, W2 (each 64x64): wt[m][r*64+c] = W[c][r]
__global__ void prep_w(const float* __restrict__ Wff, const float* __restrict__ W1,
                       const float* __restrict__ W2, unsigned short* __restrict__ wt) {
    int idx = blockIdx.x * 256 + threadIdx.x;
    if (idx >= 3 * 4096) return;
    int m = idx >> 12, rc = idx & 4095, r = rc >> 6, c = rc & 63;
    const float* W = (m == 0) ? Wff : (m == 1) ? W1 : W2;
    unsigned short u; short s = f2bf(W[c * 64 + r]);
    __builtin_memcpy(&u, &s, 2);
    wt[idx] = u;
}

__global__ __launch_bounds__(512, 4)
void ta_mfma5(const float* __restrict__ x,
              const float* __restrict__ steP,
              const float* __restrict__ steQ,
              const float* __restrict__ bff, const float* __restrict__ b1,
              const float* __restrict__ b2,
              const unsigned short* __restrict__ wt,
              float* __restrict__ out)
{
    alignas(16) __shared__ char smem[LDSZ];

    const int tid = threadIdx.x;
    const int w   = tid >> 6;
    const int l   = tid & 63;
    const int l15 = l & 15;
    const int l4  = l >> 4;
    const int b   = blockIdx.y;
    const int n0  = blockIdx.x * 8;

    // vT p-pad zeros: (n*64+d) == tid covers all 512 rows, bytes 24..31 (p 12..15)
    *(long long*)(smem + VTOFS + tid * 32 + 24) = 0LL;

    // ---- W_ff B-frags (bf16, pre-transposed in d_ws) ----
    bf16x8 wf[4][2];
    float bfv[4];
    #pragma unroll
    for (int nt = 0; nt < 4; ++nt) {
        bfv[nt] = bff[nt * 16 + l15];
        #pragma unroll
        for (int kc = 0; kc < 2; ++kc)
            wf[nt][kc] = *(const bf16x8*)(wt + (nt * 16 + l15) * 64 + kc * 32 + l4 * 8);
    }

    // ---- phase 1: projections, 18 jobs = 3 tensors x 6 s-pairs ----
    const int sA = l15 >> 3, nA = l15 & 7;
    for (int job = w; job < 18; job += 8) {
        const int t = job / 6, s0 = (job % 6) * 2;
        const float* base = (t == 0) ? steQ : (t == 1) ? steP : x;
        const float* rp = base + ((size_t)(b * Ss + s0 + sA) * Nn + n0 + nA) * Dd + l4 * 8;

        bf16x8 a[2];
        #pragma unroll
        for (int kc = 0; kc < 2; ++kc) {
            float4 p0 = *(const float4*)(rp + kc * 32);
            float4 p1 = *(const float4*)(rp + kc * 32 + 4);
            union { unsigned u[4]; bf16x8 v; } cv;
            cv.u[0] = cvtpk(p0.x, p0.y); cv.u[1] = cvtpk(p0.z, p0.w);
            cv.u[2] = cvtpk(p1.x, p1.y); cv.u[3] = cvtpk(p1.z, p1.w);
            a[kc] = cv.v;
        }
        #pragma unroll
        for (int nt = 0; nt < 4; ++nt) {
            f32x4 acc = { bfv[nt], bfv[nt], bfv[nt], bfv[nt] };
            acc = MFMA16(a[0], wf[nt][0], acc);
            acc = MFMA16(a[1], wf[nt][1], acc);
            const int d = nt * 16 + l15;
            #pragma unroll
            for (int q = 0; q < 4; ++q) {
                const int r = l4 * 4 + q, s = s0 + (r >> 3), nn = r & 7;
                if (t < 2) *(short*)(smem + qkOfs(t, s, nn, d)) = f2bf(acc[q]);
                else       *(short*)(smem + vtOfs(nn, d, s))   = f2bf(acc[q]);
            }
        }
    }
    __syncthreads();   // B1: q,k,vT ready

    // ---- phase 2a: per-head QK^T (swapped) + softmax; P packed in regs ----
    const int n = w;
    unsigned pw[8][2];
    #pragma unroll
    for (int h = 0; h < 8; ++h) {
        // broadcast reads: all l4 groups load the same 16 addresses (s = l15)
        union { unsigned u[4]; bf16x8 v; } akk;
        akk.v = *(const bf16x8*)(smem + qkOfs(1, l15, n, h * 8));
        bf16x8 aq = *(const bf16x8*)(smem + qkOfs(0, l15, n, h * 8));
        if (l4 != 0) { akk.u[0] = 0; akk.u[1] = 0; akk.u[2] = 0; akk.u[3] = 0; }
        f32x4 c = { 0.f, 0.f, 0.f, 0.f };
        c = MFMA16(akk.v, aq, c);     // S^T: row p = l4*4+reg, col q = l15
        float e[4];
        #pragma unroll
        for (int i = 0; i < 4; ++i) {
            float v = __builtin_amdgcn_exp2f(c[i] * EXPK);
            e[i] = (l4 == 3) ? 0.f : v;     // zero p >= 12 (and garbage rows)
        }
        float ssum = (e[0] + e[1]) + (e[2] + e[3]);
        ssum += __shfl_xor(ssum, 16);
        ssum += __shfl_xor(ssum, 32);
        float inv;
        asm("v_rcp_f32 %0, %1" : "=v"(inv) : "v"(ssum));
        pw[h][0] = cvtpk(e[0] * inv, e[1] * inv);
        pw[h][1] = cvtpk(e[2] * inv, e[3] * inv);
    }
    __syncthreads();   // B2: q,k slabs dead -> wave-private tbuf region usable

    // ---- phase 2b: PV per head; A via ds_bpermute; out -> wave tbuf (bf16) ----
    const int i0 = (32 * l4 + l15) * 4;
    #pragma unroll
    for (int h = 0; h < 8; ++h) {
        union { unsigned u[4]; bf16x8 v; } ap;
        ap.u[0] = (unsigned)__builtin_amdgcn_ds_bpermute(i0,      (int)pw[h][0]);
        ap.u[1] = (unsigned)__builtin_amdgcn_ds_bpermute(i0,      (int)pw[h][1]);
        ap.u[2] = (unsigned)__builtin_amdgcn_ds_bpermute(i0 + 64, (int)pw[h][0]);
        ap.u[3] = (unsigned)__builtin_amdgcn_ds_bpermute(i0 + 64, (int)pw[h][1]);
        if (l4 >= 2) { ap.u[0] = 0; ap.u[1] = 0; ap.u[2] = 0; ap.u[3] = 0; }
        // B-frag: rows k=p (l4&1 keeps p in [0,16)), col d' = h*8 + (l15&7)
        const int va = vtOfs(n, h * 8 + (l15 & 7), (l4 & 1) * 8);
        bf16x8 bv = *(const bf16x8*)(smem + va);
        f32x4 o = { 0.f, 0.f, 0.f, 0.f };
        o = MFMA16(ap.v, bv, o);   // rows q = l4*4+reg, cols d' = l15 (<8 valid)
        if (l15 < 8) {
            #pragma unroll
            for (int reg = 0; reg < 4; ++reg) {
                const int q = l4 * 4 + reg;
                if (q < 12)
                    *(short*)(smem + tOfs(w, q, h * 8 + l15)) = f2bf(o[reg]);
            }
        }
    }
    lds_fence();   // wave-local: tbuf writes before FFN reads (DS in-order)

    // ---- phase 3: FFN, fully wave-private (rows = 12 q for n = w) ----
    {
        bf16x8 w1f[4][2];
        float b1v[4];
        #pragma unroll
        for (int nt = 0; nt < 4; ++nt) {
            b1v[nt] = b1[nt * 16 + l15];
            #pragma unroll
            for (int kc = 0; kc < 2; ++kc)
                w1f[nt][kc] = *(const bf16x8*)(wt + 4096 + (nt * 16 + l15) * 64 + kc * 32 + l4 * 8);
        }
        bf16x8 a[2];
        #pragma unroll
        for (int kc = 0; kc < 2; ++kc)
            a[kc] = *(const bf16x8*)(smem + tOfs(w, l15, kc * 32 + l4 * 8));
        #pragma unroll
        for (int nt = 0; nt < 4; ++nt) {
            f32x4 acc = { b1v[nt], b1v[nt], b1v[nt], b1v[nt] };
            acc = MFMA16(a[0], w1f[nt][0], acc);
            acc = MFMA16(a[1], w1f[nt][1], acc);
            #pragma unroll
            for (int reg = 0; reg < 4; ++reg) {
                const int rt = l4 * 4 + reg;
                if (rt < 12)
                    *(short*)(smem + tOfs(w, rt, nt * 16 + l15)) =
                        f2bf(fmaxf(acc[reg], 0.f));
            }
        }
    }
    lds_fence();   // wave-local: hid writes before FFN2 reads
    {
        bf16x8 w2f[4][2];
        float b2v[4];
        #pragma unroll
        for (int nt = 0; nt < 4; ++nt) {
            b2v[nt] = b2[nt * 16 + l15];
            #pragma unroll
            for (int kc = 0; kc < 2; ++kc)
                w2f[nt][kc] = *(const bf16x8*)(wt + 8192 + (nt * 16 + l15) * 64 + kc * 32 + l4 * 8);
        }
        bf16x8 a[2];
        #pragma unroll
        for (int kc = 0; kc < 2; ++kc)
            a[kc] = *(const bf16x8*)(smem + tOfs(w, l15, kc * 32 + l4 * 8));
        #pragma unroll
        for (int nt = 0; nt < 4; ++nt) {
            f32x4 acc = { b2v[nt], b2v[nt], b2v[nt], b2v[nt] };
            acc = MFMA16(a[0], w2f[nt][0], acc);
            acc = MFMA16(a[1], w2f[nt][1], acc);
            #pragma unroll
            for (int reg = 0; reg < 4; ++reg) {
                const int q = l4 * 4 + reg;
                if (q < 12)
                    out[((size_t)(b * Ss + q) * Nn + n0 + w) * Dd + nt * 16 + l15] = acc[reg];
            }
        }
    }
}

extern "C" void kernel_launch(void* const* d_in, const int* in_sizes, int n_in,
                              void* d_out, int out_size, void* d_ws, size_t ws_size,
                              hipStream_t stream) {
    const float* x    = (const float*)d_in[0];
    const float* steP = (const float*)d_in[1];
    const float* steQ = (const float*)d_in[2];
    const float* Wff  = (const float*)d_in[3];
    const float* bff  = (const float*)d_in[4];
    const float* W1   = (const float*)d_in[5];
    const float* b1   = (const float*)d_in[6];
    const float* W2   = (const float*)d_in[7];
    const float* b2   = (const float*)d_in[8];
    float* out = (float*)d_out;
    unsigned short* wtp = (unsigned short*)d_ws;

    prep_w<<<48, 256, 0, stream>>>(Wff, W1, W2, wtp);
    dim3 grid(Nn / 8, Bb);
    ta_mfma5<<<grid, 512, 0, stream>>>(x, steP, steQ, bff, b1, b2, wtp, out);
}

// Round 9
// 151.107 us; speedup vs baseline: 2.8657x; 1.0392x over previous
//
#include <hip/hip_runtime.h>
#include <hip/hip_bf16.h>

// transformAttention fused MFMA kernel (round 9)
// Round-8 post-mortem: NaN from an unlocalizable combo of 5 changes -> revert
// to verified round-7 chassis (157us) + ONE change: v stays row-major and PV
// runs on VALU via per-wave pbuf (kills vT 16-way-conflict writes + 32
// bpermutes). Swizzle centralized in qkOfs, upgraded to ((s&7)^(n&7))<<4
// (also fixes phase-1 store group aliasing). Phase 1/2a/FFN/stores = r7.
// LDS map (36864 B, 4 blocks/CU):
//   [0,12288)      q slab [12s][8n][64d] bf16, swz ((s&7)^(n&7))<<4
//   [12288,24576)  k slab (same)   | after B2: per-wave pbuf(3072)->tbuf(2048)
//   [24576,36864)  v slab (same layout, row-major)

typedef __attribute__((ext_vector_type(8))) short bf16x8;
typedef __attribute__((ext_vector_type(4))) float f32x4;

constexpr int Bb = 16, Ss = 12, Nn = 2048, Dd = 64;
constexpr float EXPK = 0.51011687f;   // (1/sqrt(8)) * log2(e)
constexpr int KOFS = 12288, VOFS = 24576, LDSZ = 36864;

#define MFMA16(A, B, C) __builtin_amdgcn_mfma_f32_16x16x32_bf16((A), (B), (C), 0, 0, 0)

__device__ __forceinline__ short f2bf(float f) {
    __hip_bfloat16 h = __float2bfloat16(f);
    short s; __builtin_memcpy(&s, &h, 2); return s;
}
__device__ __forceinline__ float bitf(unsigned u) {
    float f; __builtin_memcpy(&f, &u, 4); return f;
}
__device__ __forceinline__ float bf2f(unsigned short v) {
    return bitf(((unsigned)v) << 16);
}
__device__ __forceinline__ unsigned cvtpk(float lo, float hi) {
    unsigned r;
    asm("v_cvt_pk_bf16_f32 %0, %1, %2" : "=v"(r) : "v"(lo), "v"(hi));
    return r;
}
__device__ __forceinline__ void lds_fence() {
    asm volatile("s_waitcnt lgkmcnt(0)" ::: "memory");
    __builtin_amdgcn_sched_barrier(0);
}
// q/k/v slab byte offset (single source of truth for the swizzle)
__device__ __forceinline__ int qkOfs(int t, int s, int n, int d) {
    return t * KOFS + s * 1024 + n * 128 + ((2 * d) ^ (((s & 7) ^ (n & 7)) << 4));
}
// per-wave attn-out/hid buffer [16 rows][64 d] bf16 (r7 verbatim)
__device__ __forceinline__ int tOfs(int w, int row, int d) {
    return w * 3072 + row * 128 + ((2 * d) ^ ((row & 7) << 4));
}

// prep: d_ws <- bf16 W^T for Wff, W1, W2: wt[m][r*64+c] = W[c][r]
__global__ void prep_w(const float* __restrict__ Wff, const float* __restrict__ W1,
                       const float* __restrict__ W2, unsigned short* __restrict__ wt) {
    int idx = blockIdx.x * 256 + threadIdx.x;
    if (idx >= 3 * 4096) return;
    int m = idx >> 12, rc = idx & 4095, r = rc >> 6, c = rc & 63;
    const float* W = (m == 0) ? Wff : (m == 1) ? W1 : W2;
    unsigned short u; short s = f2bf(W[c * 64 + r]);
    __builtin_memcpy(&u, &s, 2);
    wt[idx] = u;
}

__global__ __launch_bounds__(512, 4)
void ta_mfma7(const float* __restrict__ x,
              const float* __restrict__ steP,
              const float* __restrict__ steQ,
              const float* __restrict__ bff, const float* __restrict__ b1,
              const float* __restrict__ b2,
              const unsigned short* __restrict__ wt,
              float* __restrict__ out)
{
    alignas(16) __shared__ char smem[LDSZ];

    const int tid = threadIdx.x;
    const int w   = tid >> 6;
    const int l   = tid & 63;
    const int l15 = l & 15;
    const int l4  = l >> 4;
    const int b   = blockIdx.y;
    const int n0  = blockIdx.x * 8;

    // ---- W_ff B-frags (bf16, pre-transposed in d_ws) ----
    bf16x8 wf[4][2];
    float bfv[4];
    #pragma unroll
    for (int nt = 0; nt < 4; ++nt) {
        bfv[nt] = bff[nt * 16 + l15];
        #pragma unroll
        for (int kc = 0; kc < 2; ++kc)
            wf[nt][kc] = *(const bf16x8*)(wt + (nt * 16 + l15) * 64 + kc * 32 + l4 * 8);
    }

    // ---- phase 1: projections, 18 jobs = 3 tensors x 6 s-pairs ----
    const int sA = l15 >> 3, nA = l15 & 7;
    for (int job = w; job < 18; job += 8) {
        const int t = job / 6, s0 = (job % 6) * 2;
        const float* base = (t == 0) ? steQ : (t == 1) ? steP : x;
        const float* rp = base + ((size_t)(b * Ss + s0 + sA) * Nn + n0 + nA) * Dd + l4 * 8;

        bf16x8 a[2];
        #pragma unroll
        for (int kc = 0; kc < 2; ++kc) {
            float4 p0 = *(const float4*)(rp + kc * 32);
            float4 p1 = *(const float4*)(rp + kc * 32 + 4);
            union { unsigned u[4]; bf16x8 v; } cv;
            cv.u[0] = cvtpk(p0.x, p0.y); cv.u[1] = cvtpk(p0.z, p0.w);
            cv.u[2] = cvtpk(p1.x, p1.y); cv.u[3] = cvtpk(p1.z, p1.w);
            a[kc] = cv.v;
        }
        #pragma unroll
        for (int nt = 0; nt < 4; ++nt) {
            f32x4 acc = { bfv[nt], bfv[nt], bfv[nt], bfv[nt] };
            acc = MFMA16(a[0], wf[nt][0], acc);
            acc = MFMA16(a[1], wf[nt][1], acc);
            const int d = nt * 16 + l15;
            #pragma unroll
            for (int q = 0; q < 4; ++q) {
                const int r = l4 * 4 + q, s = s0 + (r >> 3), nn = r & 7;
                *(short*)(smem + qkOfs(t, s, nn, d)) = f2bf(acc[q]);
            }
        }
    }
    __syncthreads();   // B1: q,k,v ready

    // ---- v rows into regs (lane = d) ----
    const int n = w;
    float vv[12];
    #pragma unroll
    for (int s = 0; s < 12; ++s)
        vv[s] = bf2f(*(const unsigned short*)(smem + qkOfs(2, s, n, l)));

    // ---- phase 2a: per-head QK^T (swapped) + softmax; P packed in regs ----
    unsigned pw[8][2];
    #pragma unroll
    for (int h = 0; h < 8; ++h) {
        union { unsigned u[4]; bf16x8 v; } akk;
        akk.v = *(const bf16x8*)(smem + qkOfs(1, l15, n, h * 8));
        bf16x8 aq = *(const bf16x8*)(smem + qkOfs(0, l15, n, h * 8));
        if (l4 != 0) { akk.u[0] = 0; akk.u[1] = 0; akk.u[2] = 0; akk.u[3] = 0; }
        f32x4 c = { 0.f, 0.f, 0.f, 0.f };
        c = MFMA16(akk.v, aq, c);     // S^T: row p = l4*4+reg, col q = l15
        float e[4];
        #pragma unroll
        for (int i = 0; i < 4; ++i) {
            float v = __builtin_amdgcn_exp2f(c[i] * EXPK);
            e[i] = (l4 == 3) ? 0.f : v;     // zero p >= 12 / garbage rows
        }
        float ssum = (e[0] + e[1]) + (e[2] + e[3]);
        ssum += __shfl_xor(ssum, 16);
        ssum += __shfl_xor(ssum, 32);
        float inv;
        asm("v_rcp_f32 %0, %1" : "=v"(inv) : "v"(ssum));
        pw[h][0] = cvtpk(e[0] * inv, e[1] * inv);
        pw[h][1] = cvtpk(e[2] * inv, e[3] * inv);
    }
    __syncthreads();   // B2: q,k slabs dead -> per-wave pbuf/tbuf region

    // ---- phase 2b: pbuf scatter + VALU PV ----
    // pbuf: [q(12) x 256B] rows; each row = 8 h-slots of 32B (16 p as bf16),
    // h-slot XOR-permuted by (q&7)<<5; p=12..15 words are zeros (l4==3 lanes).
    const int pb = w * 3072;
    if (l15 < 12) {
        #pragma unroll
        for (int h = 0; h < 8; ++h) {
            uint2 u; u.x = pw[h][0]; u.y = pw[h][1];
            *(uint2*)(smem + pb + l15 * 256 + ((h * 32) ^ ((l15 & 7) << 5)) + l4 * 8) = u;
        }
    }
    lds_fence();

    float oacc[12];
    const int hslot = (l >> 3) * 32;   // lane's head = d>>3
    #pragma unroll
    for (int q = 0; q < 12; ++q) {
        const char* qp = smem + pb + q * 256 + (hslot ^ ((q & 7) << 5));
        float a = 0.f;
        #pragma unroll
        for (int p2 = 0; p2 < 6; ++p2) {
            unsigned pd = *(const unsigned*)(qp + p2 * 4);
            a = fmaf(bitf(pd << 16),         vv[2 * p2],     a);
            a = fmaf(bitf(pd & 0xFFFF0000u), vv[2 * p2 + 1], a);
        }
        oacc[q] = a;
    }
    lds_fence();   // pbuf reads complete before tbuf overwrites same region

    #pragma unroll
    for (int q = 0; q < 12; ++q)
        *(short*)(smem + tOfs(w, q, l)) = f2bf(oacc[q]);
    lds_fence();

    // ---- phase 3: FFN, fully wave-private (rows = 12 q for n = w) ----
    {
        bf16x8 w1f[4][2];
        float b1v[4];
        #pragma unroll
        for (int nt = 0; nt < 4; ++nt) {
            b1v[nt] = b1[nt * 16 + l15];
            #pragma unroll
            for (int kc = 0; kc < 2; ++kc)
                w1f[nt][kc] = *(const bf16x8*)(wt + 4096 + (nt * 16 + l15) * 64 + kc * 32 + l4 * 8);
        }
        bf16x8 a[2];
        #pragma unroll
        for (int kc = 0; kc < 2; ++kc)
            a[kc] = *(const bf16x8*)(smem + tOfs(w, l15, kc * 32 + l4 * 8));
        #pragma unroll
        for (int nt = 0; nt < 4; ++nt) {
            f32x4 acc = { b1v[nt], b1v[nt], b1v[nt], b1v[nt] };
            acc = MFMA16(a[0], w1f[nt][0], acc);
            acc = MFMA16(a[1], w1f[nt][1], acc);
            #pragma unroll
            for (int reg = 0; reg < 4; ++reg) {
                const int rt = l4 * 4 + reg;
                if (rt < 12)
                    *(short*)(smem + tOfs(w, rt, nt * 16 + l15)) =
                        f2bf(fmaxf(acc[reg], 0.f));
            }
        }
    }
    lds_fence();   // wave-local: hid writes before FFN2 reads
    {
        bf16x8 w2f[4][2];
        float b2v[4];
        #pragma unroll
        for (int nt = 0; nt < 4; ++nt) {
            b2v[nt] = b2[nt * 16 + l15];
            #pragma unroll
            for (int kc = 0; kc < 2; ++kc)
                w2f[nt][kc] = *(const bf16x8*)(wt + 8192 + (nt * 16 + l15) * 64 + kc * 32 + l4 * 8);
        }
        bf16x8 a[2];
        #pragma unroll
        for (int kc = 0; kc < 2; ++kc)
            a[kc] = *(const bf16x8*)(smem + tOfs(w, l15, kc * 32 + l4 * 8));
        #pragma unroll
        for (int nt = 0; nt < 4; ++nt) {
            f32x4 acc = { b2v[nt], b2v[nt], b2v[nt], b2v[nt] };
            acc = MFMA16(a[0], w2f[nt][0], acc);
            acc = MFMA16(a[1], w2f[nt][1], acc);
            #pragma unroll
            for (int reg = 0; reg < 4; ++reg) {
                const int q = l4 * 4 + reg;
                if (q < 12)
                    out[((size_t)(b * Ss + q) * Nn + n0 + w) * Dd + nt * 16 + l15] = acc[reg];
            }
        }
    }
}

extern "C" void kernel_launch(void* const* d_in, const int* in_sizes, int n_in,
                              void* d_out, int out_size, void* d_ws, size_t ws_size,
                              hipStream_t stream) {
    const float* x    = (const float*)d_in[0];
    const float* steP = (const float*)d_in[1];
    const float* steQ = (const float*)d_in[2];
    const float* Wff  = (const float*)d_in[3];
    const float* bff  = (const float*)d_in[4];
    const float* W1   = (const float*)d_in[5];
    const float* b1   = (const float*)d_in[6];
    const float* W2   = (const float*)d_in[7];
    const float* b2   = (const float*)d_in[8];
    float* out = (float*)d_out;
    unsigned short* wtp = (unsigned short*)d_ws;

    prep_w<<<48, 256, 0, stream>>>(Wff, W1, W2, wtp);
    dim3 grid(Nn / 8, Bb);
    ta_mfma7<<<grid, 512, 0, stream>>>(x, steP, steQ, bff, b1, b2, wtp, out);
}

// Round 10
// 127.613 us; speedup vs baseline: 3.3933x; 1.1841x over previous
//
#include <hip/hip_runtime.h>
#include <hip/hip_bf16.h>

// transformAttention fused MFMA kernel (round 10)
// Round-9 post-mortem: no pipe >40%; waves ~90% stalled on serial latency
// chains (1 attn chain per wave). Round 10: same math/layouts as r9, but
// 256-thread blocks (4 waves) with 2 n-positions per wave, fully unrolled ->
// two independent latency chains interleaved per wave (ILP, not occupancy).
// PV LDS reads packed (b128+b64), dead l4==3 pbuf writes skipped.
// LDS map (36864 B, 4 blocks/CU):
//   [0,12288)      q slab [12s][8n][64d] bf16, swz ((s&7)^(n&7))<<4
//   [12288,24576)  k slab (same) | after B2: per-wave 6144B (2x pbuf/tbuf)
//   [24576,36864)  v slab (same layout, row-major)

typedef __attribute__((ext_vector_type(8))) short bf16x8;
typedef __attribute__((ext_vector_type(4))) float f32x4;

constexpr int Bb = 16, Ss = 12, Nn = 2048, Dd = 64;
constexpr float EXPK = 0.51011687f;   // (1/sqrt(8)) * log2(e)
constexpr int KOFS = 12288, VOFS = 24576, LDSZ = 36864;

#define MFMA16(A, B, C) __builtin_amdgcn_mfma_f32_16x16x32_bf16((A), (B), (C), 0, 0, 0)

__device__ __forceinline__ short f2bf(float f) {
    __hip_bfloat16 h = __float2bfloat16(f);
    short s; __builtin_memcpy(&s, &h, 2); return s;
}
__device__ __forceinline__ float bitf(unsigned u) {
    float f; __builtin_memcpy(&f, &u, 4); return f;
}
__device__ __forceinline__ float bf2f(unsigned short v) {
    return bitf(((unsigned)v) << 16);
}
__device__ __forceinline__ unsigned cvtpk(float lo, float hi) {
    unsigned r;
    asm("v_cvt_pk_bf16_f32 %0, %1, %2" : "=v"(r) : "v"(lo), "v"(hi));
    return r;
}
__device__ __forceinline__ void lds_fence() {
    asm volatile("s_waitcnt lgkmcnt(0)" ::: "memory");
    __builtin_amdgcn_sched_barrier(0);
}
// q/k/v slab byte offset (single source of truth for the swizzle)
__device__ __forceinline__ int qkOfs(int t, int s, int n, int d) {
    return t * KOFS + s * 1024 + n * 128 + ((2 * d) ^ (((s & 7) ^ (n & 7)) << 4));
}
// per-wave-per-ni attn-out/hid buffer [16 rows][64 d] bf16
__device__ __forceinline__ int tOfs(int w, int ni, int row, int d) {
    return w * 6144 + ni * 3072 + row * 128 + ((2 * d) ^ ((row & 7) << 4));
}

// prep: d_ws <- bf16 W^T for Wff, W1, W2: wt[m][r*64+c] = W[c][r]
__global__ void prep_w(const float* __restrict__ Wff, const float* __restrict__ W1,
                       const float* __restrict__ W2, unsigned short* __restrict__ wt) {
    int idx = blockIdx.x * 256 + threadIdx.x;
    if (idx >= 3 * 4096) return;
    int m = idx >> 12, rc = idx & 4095, r = rc >> 6, c = rc & 63;
    const float* W = (m == 0) ? Wff : (m == 1) ? W1 : W2;
    unsigned short u; short s = f2bf(W[c * 64 + r]);
    __builtin_memcpy(&u, &s, 2);
    wt[idx] = u;
}

__global__ __launch_bounds__(256, 4)
void ta_mfma8(const float* __restrict__ x,
              const float* __restrict__ steP,
              const float* __restrict__ steQ,
              const float* __restrict__ bff, const float* __restrict__ b1,
              const float* __restrict__ b2,
              const unsigned short* __restrict__ wt,
              float* __restrict__ out)
{
    alignas(16) __shared__ char smem[LDSZ];

    const int tid = threadIdx.x;
    const int w   = tid >> 6;      // 0..3
    const int l   = tid & 63;
    const int l15 = l & 15;
    const int l4  = l >> 4;
    const int b   = blockIdx.y;
    const int n0  = blockIdx.x * 8;

    // ---- W_ff B-frags (bf16, pre-transposed in d_ws) ----
    bf16x8 wf[4][2];
    float bfv[4];
    #pragma unroll
    for (int nt = 0; nt < 4; ++nt) {
        bfv[nt] = bff[nt * 16 + l15];
        #pragma unroll
        for (int kc = 0; kc < 2; ++kc)
            wf[nt][kc] = *(const bf16x8*)(wt + (nt * 16 + l15) * 64 + kc * 32 + l4 * 8);
    }

    // ---- phase 1: projections, 18 jobs = 3 tensors x 6 s-pairs, 4 waves ----
    const int sA = l15 >> 3, nA = l15 & 7;
    for (int job = w; job < 18; job += 4) {
        const int t = job / 6, s0 = (job % 6) * 2;
        const float* base = (t == 0) ? steQ : (t == 1) ? steP : x;
        const float* rp = base + ((size_t)(b * Ss + s0 + sA) * Nn + n0 + nA) * Dd + l4 * 8;

        bf16x8 a[2];
        #pragma unroll
        for (int kc = 0; kc < 2; ++kc) {
            float4 p0 = *(const float4*)(rp + kc * 32);
            float4 p1 = *(const float4*)(rp + kc * 32 + 4);
            union { unsigned u[4]; bf16x8 v; } cv;
            cv.u[0] = cvtpk(p0.x, p0.y); cv.u[1] = cvtpk(p0.z, p0.w);
            cv.u[2] = cvtpk(p1.x, p1.y); cv.u[3] = cvtpk(p1.z, p1.w);
            a[kc] = cv.v;
        }
        #pragma unroll
        for (int nt = 0; nt < 4; ++nt) {
            f32x4 acc = { bfv[nt], bfv[nt], bfv[nt], bfv[nt] };
            acc = MFMA16(a[0], wf[nt][0], acc);
            acc = MFMA16(a[1], wf[nt][1], acc);
            const int d = nt * 16 + l15;
            #pragma unroll
            for (int q = 0; q < 4; ++q) {
                const int r = l4 * 4 + q, s = s0 + (r >> 3), nn = r & 7;
                *(short*)(smem + qkOfs(t, s, nn, d)) = f2bf(acc[q]);
            }
        }
    }
    __syncthreads();   // B1: q,k,v ready

    // ---- v rows into regs (lane = d), both ni ----
    float vv[2][12];
    #pragma unroll
    for (int ni = 0; ni < 2; ++ni)
        #pragma unroll
        for (int s = 0; s < 12; ++s)
            vv[ni][s] = bf2f(*(const unsigned short*)(smem + qkOfs(2, s, w * 2 + ni, l)));

    // ---- phase 2a: per-head QK^T (swapped) + softmax; both ni interleaved ----
    unsigned pw[2][8][2];
    #pragma unroll
    for (int h = 0; h < 8; ++h) {
        #pragma unroll
        for (int ni = 0; ni < 2; ++ni) {
            const int n = w * 2 + ni;
            union { unsigned u[4]; bf16x8 v; } akk;
            akk.v = *(const bf16x8*)(smem + qkOfs(1, l15, n, h * 8));
            bf16x8 aq = *(const bf16x8*)(smem + qkOfs(0, l15, n, h * 8));
            if (l4 != 0) { akk.u[0] = 0; akk.u[1] = 0; akk.u[2] = 0; akk.u[3] = 0; }
            f32x4 c = { 0.f, 0.f, 0.f, 0.f };
            c = MFMA16(akk.v, aq, c);     // S^T: row p = l4*4+reg, col q = l15
            float e[4];
            #pragma unroll
            for (int i = 0; i < 4; ++i) {
                float v = __builtin_amdgcn_exp2f(c[i] * EXPK);
                e[i] = (l4 == 3) ? 0.f : v;     // zero p >= 12 / garbage rows
            }
            float ssum = (e[0] + e[1]) + (e[2] + e[3]);
            ssum += __shfl_xor(ssum, 16);
            ssum += __shfl_xor(ssum, 32);
            float inv;
            asm("v_rcp_f32 %0, %1" : "=v"(inv) : "v"(ssum));
            pw[ni][h][0] = cvtpk(e[0] * inv, e[1] * inv);
            pw[ni][h][1] = cvtpk(e[2] * inv, e[3] * inv);
        }
    }
    __syncthreads();   // B2: q,k slabs dead -> per-wave pbuf/tbuf region

    // ---- phase 2b: pbuf scatter + VALU PV, both ni ----
    // pbuf: [q(12) x 256B] rows; each row = 8 h-slots of 32B (16 p as bf16),
    // h-slot XOR-permuted by (q&7)<<5. Only p 0..11 (24B/slot) ever read.
    #pragma unroll
    for (int ni = 0; ni < 2; ++ni) {
        const int pb = w * 6144 + ni * 3072;
        if (l15 < 12 && l4 < 3) {
            #pragma unroll
            for (int h = 0; h < 8; ++h) {
                uint2 u; u.x = pw[ni][h][0]; u.y = pw[ni][h][1];
                *(uint2*)(smem + pb + l15 * 256 + ((h * 32) ^ ((l15 & 7) << 5)) + l4 * 8) = u;
            }
        }
    }
    lds_fence();

    float oacc[2][12];
    const int hslot = (l >> 3) * 32;   // lane's head = d>>3
    #pragma unroll
    for (int q = 0; q < 12; ++q) {
        #pragma unroll
        for (int ni = 0; ni < 2; ++ni) {
            const char* qp = smem + w * 6144 + ni * 3072 + q * 256 + (hslot ^ ((q & 7) << 5));
            uint4 pa = *(const uint4*)(qp);
            uint2 pbx = *(const uint2*)(qp + 16);
            const unsigned wds[6] = { pa.x, pa.y, pa.z, pa.w, pbx.x, pbx.y };
            float a = 0.f;
            #pragma unroll
            for (int p2 = 0; p2 < 6; ++p2) {
                a = fmaf(bitf(wds[p2] << 16),         vv[ni][2 * p2],     a);
                a = fmaf(bitf(wds[p2] & 0xFFFF0000u), vv[ni][2 * p2 + 1], a);
            }
            oacc[ni][q] = a;
        }
    }
    lds_fence();   // pbuf reads complete before tbuf overwrites same region

    #pragma unroll
    for (int ni = 0; ni < 2; ++ni)
        #pragma unroll
        for (int q = 0; q < 12; ++q)
            *(short*)(smem + tOfs(w, ni, q, l)) = f2bf(oacc[ni][q]);
    lds_fence();

    // ---- phase 3: FFN, wave-private, both ni ----
    {
        bf16x8 w1f[4][2];
        float b1v[4];
        #pragma unroll
        for (int nt = 0; nt < 4; ++nt) {
            b1v[nt] = b1[nt * 16 + l15];
            #pragma unroll
            for (int kc = 0; kc < 2; ++kc)
                w1f[nt][kc] = *(const bf16x8*)(wt + 4096 + (nt * 16 + l15) * 64 + kc * 32 + l4 * 8);
        }
        #pragma unroll
        for (int ni = 0; ni < 2; ++ni) {
            bf16x8 a[2];
            #pragma unroll
            for (int kc = 0; kc < 2; ++kc)
                a[kc] = *(const bf16x8*)(smem + tOfs(w, ni, l15, kc * 32 + l4 * 8));
            #pragma unroll
            for (int nt = 0; nt < 4; ++nt) {
                f32x4 acc = { b1v[nt], b1v[nt], b1v[nt], b1v[nt] };
                acc = MFMA16(a[0], w1f[nt][0], acc);
                acc = MFMA16(a[1], w1f[nt][1], acc);
                #pragma unroll
                for (int reg = 0; reg < 4; ++reg) {
                    const int rt = l4 * 4 + reg;
                    if (rt < 12)
                        *(short*)(smem + tOfs(w, ni, rt, nt * 16 + l15)) =
                            f2bf(fmaxf(acc[reg], 0.f));
                }
            }
        }
    }
    lds_fence();   // wave-local: hid writes before FFN2 reads
    {
        bf16x8 w2f[4][2];
        float b2v[4];
        #pragma unroll
        for (int nt = 0; nt < 4; ++nt) {
            b2v[nt] = b2[nt * 16 + l15];
            #pragma unroll
            for (int kc = 0; kc < 2; ++kc)
                w2f[nt][kc] = *(const bf16x8*)(wt + 8192 + (nt * 16 + l15) * 64 + kc * 32 + l4 * 8);
        }
        #pragma unroll
        for (int ni = 0; ni < 2; ++ni) {
            bf16x8 a[2];
            #pragma unroll
            for (int kc = 0; kc < 2; ++kc)
                a[kc] = *(const bf16x8*)(smem + tOfs(w, ni, l15, kc * 32 + l4 * 8));
            #pragma unroll
            for (int nt = 0; nt < 4; ++nt) {
                f32x4 acc = { b2v[nt], b2v[nt], b2v[nt], b2v[nt] };
                acc = MFMA16(a[0], w2f[nt][0], acc);
                acc = MFMA16(a[1], w2f[nt][1], acc);
                #pragma unroll
                for (int reg = 0; reg < 4; ++reg) {
                    const int q = l4 * 4 + reg;
                    if (q < 12)
                        out[((size_t)(b * Ss + q) * Nn + n0 + w * 2 + ni) * Dd + nt * 16 + l15] = acc[reg];
                }
            }
        }
    }
}

extern "C" void kernel_launch(void* const* d_in, const int* in_sizes, int n_in,
                              void* d_out, int out_size, void* d_ws, size_t ws_size,
                              hipStream_t stream) {
    const float* x    = (const float*)d_in[0];
    const float* steP = (const float*)d_in[1];
    const float* steQ = (const float*)d_in[2];
    const float* Wff  = (const float*)d_in[3];
    const float* bff  = (const float*)d_in[4];
    const float* W1   = (const float*)d_in[5];
    const float* b1   = (const float*)d_in[6];
    const float* W2   = (const float*)d_in[7];
    const float* b2   = (const float*)d_in[8];
    float* out = (float*)d_out;
    unsigned short* wtp = (unsigned short*)d_ws;

    prep_w<<<48, 256, 0, stream>>>(Wff, W1, W2, wtp);
    dim3 grid(Nn / 8, Bb);
    ta_mfma8<<<grid, 256, 0, stream>>>(x, steP, steQ, bff, b1, b2, wtp, out);
}